// Round 3
// baseline (184.808 us; speedup 1.0000x reference)
//
#include <hip/hip_runtime.h>

typedef unsigned long long ull;
#define NW 1024          // 64-bit words per image bitmap (256*256/64)
#define BIG (1 << 29)    // sentinel: no further set bit

// ---------- Stage 1: mask ballot + contour bit-ops, banded ----------
__global__ __launch_bounds__(1024)
void contour_build_kernel(const float* __restrict__ target,
                          ull* __restrict__ cwg,
                          float* __restrict__ out) {
    __shared__ ull lb[34 * 4];  // 34 window rows x 4 words

    const int img  = blockIdx.x;
    const int band = blockIdx.y;
    const int tid  = threadIdx.x;
    const int wave = tid >> 6, lane = tid & 63;

    if (img == 0 && band == 0 && tid == 0) out[0] = 0.0f;  // replaces memset

    const float* imgp = target + (size_t)img * 131072 + 65536;  // channel 1
    const int r0 = band * 32 - 1;  // global row of window row 0

    // Window rows: wave handles {wave, wave+16, wave+32(<34)} -> 2-3 iters,
    // each issuing 4 independent coalesced row-word loads.
    for (int wr = wave; wr < 34; wr += 16) {
        const int gr = r0 + wr;
        const bool inb = (gr >= 0 && gr <= 255);
        const float* rowp = imgp + ((size_t)(inb ? gr : 0) << 8);
        float v0 = inb ? rowp[lane]        : 0.0f;
        float v1 = inb ? rowp[64 + lane]   : 0.0f;
        float v2 = inb ? rowp[128 + lane]  : 0.0f;
        float v3 = inb ? rowp[192 + lane]  : 0.0f;
        ull b0 = __ballot(v0 > 0.5f);
        ull b1 = __ballot(v1 > 0.5f);
        ull b2 = __ballot(v2 > 0.5f);
        ull b3 = __ballot(v3 > 0.5f);
        if (lane == 0) {
            lb[wr * 4 + 0] = b0; lb[wr * 4 + 1] = b1;
            lb[wr * 4 + 2] = b2; lb[wr * 4 + 3] = b3;
        }
    }
    __syncthreads();

    // Contour for the 32 owned rows = 128 words (same bit-ops as validated).
    if (tid < 128) {
        const int k  = tid;
        const int lr = 1 + (k >> 2);   // window row 1..32
        const int wp = k & 3;
        auto get = [&](int rr, int ww) -> ull {
            return (ww < 0 || ww > 3) ? 0ULL : lb[(rr << 2) + ww];
        };
        ull A  = get(lr - 1, wp);
        ull C  = lb[(lr << 2) + wp];
        ull Bx = get(lr + 1, wp);
        ull Ap = get(lr - 1, wp - 1), An = get(lr - 1, wp + 1);
        ull Cp = get(lr,     wp - 1), Cn = get(lr,     wp + 1);
        ull Bp = get(lr + 1, wp - 1), Bn = get(lr + 1, wp + 1);
        ull interior =
            ((A  << 1) | (Ap >> 63)) & A  & ((A  >> 1) | (An << 63)) &
            ((C  << 1) | (Cp >> 63)) &      ((C  >> 1) | (Cn << 63)) &
            ((Bx << 1) | (Bp >> 63)) & Bx & ((Bx >> 1) | (Bn << 63));
        cwg[(size_t)img * NW + band * 128 + k] = C & ~interior;
    }
}

// ---------- Stage 2 helpers ----------
// First set bit at absolute position >= q, scanning global words. BIG if none.
__device__ __forceinline__ int next_g(const ull* __restrict__ cw, int q) {
    int w = q >> 6;
    if (w >= NW) return BIG;
    const int b = q & 63;
    ull m = cw[w] >> b;               // bits >= q (b in 0..63)
    if (m) return q + __builtin_ctzll(m);
    while (++w < NW) {
        ull t = cw[w];
        if (t) return (w << 6) + __builtin_ctzll(t);
    }
    return BIG;
}

// Next set bit strictly after absolute pos `apos`, using the 128-bit register
// window [base, base+128) (lo,hi); falls back to global scan past the window.
__device__ __forceinline__ int win_next(ull lo, ull hi, int base,
                                        const ull* __restrict__ cw, int apos) {
    const int rel = apos - base;
    if (rel < 127) {
        const int s = rel + 1;        // 1..127
        if (s < 64) {
            ull m = lo >> s;          // shift 1..63
            if (m) return apos + 1 + __builtin_ctzll(m);
            if (hi) return base + 64 + __builtin_ctzll(hi);
        } else {
            ull m = hi >> (s - 64);   // shift 0..63
            if (m) return apos + 1 + __builtin_ctzll(m);
        }
        return next_g(cw, base + 128);
    }
    return next_g(cw, apos + 1);
}

// ---------- Stage 2: consecutive-triple bending energy, LDS-free ----------
__global__ __launch_bounds__(256)
void bending_energy_kernel(const ull* __restrict__ cwg,
                           float* __restrict__ out, float inv_b) {
#pragma clang fp contract(off)
    __shared__ float wsum[4];

    const int img   = blockIdx.x;
    const int chunk = blockIdx.y * 256 + threadIdx.x;  // owned byte 0..8191
    const int tid   = threadIdx.x;
    const int wave  = tid >> 6, lane = tid & 63;

    const ull* cw = cwg + (size_t)img * NW;
    const int k  = chunk >> 3;
    const int sh = (chunk & 7) << 3;                   // 0,8,...,56
    const ull w0 = cw[k];
    const ull w1 = (k + 1 < NW) ? cw[k + 1] : 0ULL;
    const ull w2 = (k + 2 < NW) ? cw[k + 2] : 0ULL;
    // 128-bit window starting at bit base = chunk*8 (shift-by-64 safe form).
    const ull lo = (w0 >> sh) | ((w1 << 1) << (63 - sh));
    const ull hi = (w1 >> sh) | ((w2 << 1) << (63 - sh));
    const int base = chunk << 3;

    float sum = 0.0f;
    const unsigned int byte = (unsigned int)(lo & 0xFFULL);
    if (byte) {
        const int lim = base + 8;
        int p0 = base + __builtin_ctz(byte);
        int p1 = win_next(lo, hi, base, cw, p0);
        int p2 = (p1 < BIG) ? win_next(lo, hi, base, cw, p1) : BIG;
        while (p0 < lim && p2 < BIG) {
            float r0f = (float)(p0 >> 8), c0f = (float)(p0 & 255);
            float r1f = (float)(p1 >> 8), c1f = (float)(p1 & 255);
            float r2f = (float)(p2 >> 8), c2f = (float)(p2 & 255);
            float v1r = r1f - r0f, v1c = c1f - c0f;
            float v2r = r2f - r1f, v2c = c2f - c1f;
            float cross = v1r * v2c - v1c * v2r;   // exact (small ints)
            if (cross != 0.0f) {
                float dot = v1r * v2r + v1c * v2c; // exact
                float n1 = sqrtf(v1r * v1r + v1c * v1c);
                float n2 = sqrtf(v2r * v2r + v2c * v2c);
                float curv = (2.0f * fabsf(cross)) / (n1 * n2 + dot);
                float factor = (cross >= 0.0f) ? 1.0f : 0.75f; // MU
                sum += (factor * (curv * curv)) / (n1 + n2);
            }
            p0 = p1; p1 = p2;
            p2 = win_next(lo, hi, base, cw, p2);
        }
    }

    for (int off = 32; off > 0; off >>= 1) sum += __shfl_down(sum, off);
    if (lane == 0) wsum[wave] = sum;
    __syncthreads();
    if (tid == 0) {
        float t = wsum[0] + wsum[1] + wsum[2] + wsum[3];
        atomicAdd(out, t * inv_b);
    }
}

extern "C" void kernel_launch(void* const* d_in, const int* in_sizes, int n_in,
                              void* d_out, int out_size, void* d_ws, size_t ws_size,
                              hipStream_t stream) {
    const float* target = (const float*)d_in[1];
    float* out = (float*)d_out;
    const int B = in_sizes[1] / (2 * 256 * 256);
    ull* cwg = (ull*)d_ws;  // B * 1024 * 8 bytes = 1 MiB

    contour_build_kernel<<<dim3(B, 8), dim3(1024), 0, stream>>>(target, cwg, out);
    bending_energy_kernel<<<dim3(B, 32), dim3(256), 0, stream>>>(cwg, out, 1.0f / (float)B);
}